// Round 16
// baseline (300.481 us; speedup 1.0000x reference)
//
#include <hip/hip_runtime.h>

typedef __attribute__((ext_vector_type(8))) short bf16x8;
typedef __attribute__((ext_vector_type(4))) float f32x4;

#define MFMA(a,b,c) __builtin_amdgcn_mfma_f32_16x16x32_bf16(a,b,c,0,0,0)

static __device__ __forceinline__ unsigned short f2bf(float f){
  unsigned u = __float_as_uint(f);
  u += 0x7FFF + ((u>>16)&1);
  return (unsigned short)(u>>16);
}
static __device__ __forceinline__ float bf2f(unsigned short b){
  return __uint_as_float(((unsigned)b)<<16);
}

// ---------------- kernel 0: weight swizzle into MFMA fragment order, bf16 hi/lo ----
__global__ __launch_bounds__(256) void wswz(
    const float* __restrict__ wk1, const float* __restrict__ wk2, const float* __restrict__ wk3,
    const float* __restrict__ wq1, const float* __restrict__ wq2, const float* __restrict__ wq3,
    unsigned short* __restrict__ wb)
{
  int y = blockIdx.y;            // net*3 + layer
  int net = y / 3, layer = y % 3;
  const float* src = net ? (layer==0?wq1: layer==1?wq2:wq3)
                         : (layer==0?wk1: layer==1?wk2:wk3);
  int N  = (layer==2) ? 32 : 128;
  int NT = N / 16;
  int total = 32 * NT * 4 * 64;
  int e = blockIdx.x * 256 + threadIdx.x;
  if (e >= total) return;
  int lane = e & 63;
  int ks   = (e >> 6) & 3;
  int nt   = (e >> 8) % NT;
  int h    = (e >> 8) / NT;
  int k0 = ks*32 + 8*(lane>>4);
  int n0 = nt*16 + (lane&15);
  const float* s = src + (size_t)h*128*N + (size_t)k0*N + n0;
  unsigned short hi[8], lo[8];
  #pragma unroll
  for (int j=0;j<8;++j){
    float v = s[(size_t)j*N];
    unsigned short hh = f2bf(v);
    hi[j] = hh;
    lo[j] = f2bf(v - bf2f(hh));
  }
  size_t nb   = (size_t)net * 2359296;
  size_t loff = (layer==0) ? 0 : (layer==1) ? 1048576 : 2097152;
  size_t losz = (layer==2) ? 131072 : 524288;
  size_t eidx = ((((size_t)h*NT + nt)*4 + ks)*64 + lane)*8;
  unsigned short* dH = wb + nb + loff + eidx;
  unsigned short* dL = dH + losz;
  *(bf16x8*)dH = *(const bf16x8*)hi;
  *(bf16x8*)dL = *(const bf16x8*)lo;
}

// ---------------- kernel 1 v6: R10 lift + ZERO-TILE TAIL ----------------
// R16 change (one mechanism): the 480MB of upper-triangle zeros move from
// scores_k into a store-only TAIL here. Same 4096 blocks / residency as the
// 318-config (unlike R6's separate zero blocks); tails of early blocks overlap
// later blocks' compute, using the write pipe that idles during lift. Block b
// zeroes zids [(b*7680)>>12, ((b+1)*7680)>>12) — bijective, balanced 1-2 tiles.
// MLP body byte-identical to R10 (318/287/280 lineage).
__global__ __launch_bounds__(256,3) void lift(
    const float* __restrict__ Kin, const float* __restrict__ Qin,
    const float* __restrict__ bk1, const float* __restrict__ bk2, const float* __restrict__ bk3,
    const float* __restrict__ bq1, const float* __restrict__ bq2, const float* __restrict__ bq3,
    const unsigned short* __restrict__ wb,
    unsigned short* __restrict__ qlift, unsigned short* __restrict__ klift,
    float* __restrict__ kout, float* __restrict__ oscores)
{
  __shared__ unsigned short XH[64][136];
  __shared__ unsigned short XL[64][136];
  int bid = blockIdx.x;
  int h   = (bid & 7)*4 + ((bid>>3)&3);   // XCD-packed head index
  int st  = (bid>>5) & 31;
  int bb  = (bid>>10) & 1;
  int net = bid>>11;
  size_t rowbase = (size_t)(bb*32 + h)*2048 + (size_t)st*64;
  const float* X = (net ? Qin : Kin) + rowbase*128;
  const unsigned short* wn = wb + (size_t)net*2359296;
  const float* b1 = (net ? bq1 : bk1) + h*128;
  const float* b2 = (net ? bq2 : bk2) + h*128;
  const float* b3 = (net ? bq3 : bk3) + h*32;
  unsigned short* lifto = net ? qlift : klift;

  int tid = threadIdx.x, w = tid >> 6, l = tid & 63;
  int lr = l & 15, lg = l >> 4;
  int acol0 = 8*lg;

  // stage 64 rows x 128 cols as trunc-split hi/lo into LDS (block-wide)
  #pragma unroll
  for (int i=0;i<8;++i){
    int row = i*8 + (tid>>5);
    int col = (tid&31)*4;
    float4 v = *(const float4*)&X[(size_t)row*128 + col];
    unsigned u0=__float_as_uint(v.x), u1=__float_as_uint(v.y),
             u2=__float_as_uint(v.z), u3=__float_as_uint(v.w);
    float l0 = v.x - __uint_as_float(u0 & 0xFFFF0000u);
    float l1 = v.y - __uint_as_float(u1 & 0xFFFF0000u);
    float l2 = v.z - __uint_as_float(u2 & 0xFFFF0000u);
    float l3 = v.w - __uint_as_float(u3 & 0xFFFF0000u);
    *(uint2*)&XH[row][col] = make_uint2((u0>>16) | (u1 & 0xFFFF0000u),
                                        (u2>>16) | (u3 & 0xFFFF0000u));
    *(uint2*)&XL[row][col] = make_uint2((__float_as_uint(l0)>>16) | (__float_as_uint(l1) & 0xFFFF0000u),
                                        (__float_as_uint(l2)>>16) | (__float_as_uint(l3) & 0xFFFF0000u));
  }
  __syncthreads();

  // ================= layers 1 & 2 (K=128 -> N=128, silu) =================
  for (int L=0; L<2; ++L){
    const unsigned short* wH = wn + (size_t)L*1048576;
    const unsigned short* wL = wH + 524288;
    const float* bias = L ? b2 : b1;
    f32x4 acc[2][4];
    #pragma unroll
    for (int ntl=0;ntl<2;++ntl)
      #pragma unroll
      for (int rt=0;rt<4;++rt)
        acc[ntl][rt] = (f32x4){0.f,0.f,0.f,0.f};

    #pragma unroll
    for (int ks=0;ks<4;++ks){
      bf16x8 bh[2], bl[2];
      #pragma unroll
      for (int ntl=0;ntl<2;++ntl){
        size_t eidx = ((((size_t)h*8 + (w*2+ntl))*4 + ks)*64 + l)*8;
        bh[ntl] = *(const bf16x8*)(wH + eidx);
        bl[ntl] = *(const bf16x8*)(wL + eidx);
      }
      #pragma unroll
      for (int rt=0;rt<4;++rt){
        bf16x8 ah = *(const bf16x8*)&XH[rt*16+lr][ks*32 + acol0];
        bf16x8 al = *(const bf16x8*)&XL[rt*16+lr][ks*32 + acol0];
        #pragma unroll
        for (int ntl=0;ntl<2;++ntl){
          f32x4 a = acc[ntl][rt];
          a = MFMA(bh[ntl], ah, a);   // Wh * Xh
          a = MFMA(bh[ntl], al, a);   // Wh * Xl
          a = MFMA(bl[ntl], ah, a);   // Wl * Xh
          acc[ntl][rt] = a;
        }
      }
    }
    __syncthreads();   // all reads of previous acts complete before overwrite
    #pragma unroll
    for (int ntl=0;ntl<2;++ntl){
      int n0 = (w*2+ntl)*16 + 4*lg;   // 4 consecutive output features
      float4 bv = *(const float4*)&bias[n0];
      float bvv[4] = {bv.x, bv.y, bv.z, bv.w};
      #pragma unroll
      for (int rt=0;rt<4;++rt){
        int row = rt*16 + lr;          // act row owned by this lane
        unsigned hh[4], ll[4];
        #pragma unroll
        for (int i=0;i<4;++i){
          float v = acc[ntl][rt][i] + bvv[i];
          float sg = v * __builtin_amdgcn_rcpf(1.f + __expf(-v));
          unsigned u = __float_as_uint(sg);
          hh[i] = u >> 16;
          float lo = sg - __uint_as_float(u & 0xFFFF0000u);
          ll[i] = __float_as_uint(lo) >> 16;
        }
        *(uint2*)&XH[row][n0] = make_uint2(hh[0] | (hh[1]<<16), hh[2] | (hh[3]<<16));
        *(uint2*)&XL[row][n0] = make_uint2(ll[0] | (ll[1]<<16), ll[2] | (ll[3]<<16));
      }
    }
    __syncthreads();
  }

  // ================= layer 3 (K=128 -> N=32, tanh) + packed stores =================
  {
    const unsigned short* wH = wn + 2097152;
    const unsigned short* wL = wH + 131072;
    int nt = w >> 1;
    int rb = (w & 1) * 2;
    f32x4 acc3[2];
    acc3[0] = (f32x4){0.f,0.f,0.f,0.f};
    acc3[1] = (f32x4){0.f,0.f,0.f,0.f};
    #pragma unroll
    for (int ks=0;ks<4;++ks){
      size_t eidx = ((((size_t)h*2 + nt)*4 + ks)*64 + l)*8;
      bf16x8 bh = *(const bf16x8*)(wH + eidx);
      bf16x8 bl = *(const bf16x8*)(wL + eidx);
      #pragma unroll
      for (int j=0;j<2;++j){
        bf16x8 ah = *(const bf16x8*)&XH[(rb+j)*16+lr][ks*32 + acol0];
        bf16x8 al = *(const bf16x8*)&XL[(rb+j)*16+lr][ks*32 + acol0];
        f32x4 a = acc3[j];
        a = MFMA(bh, ah, a);
        a = MFMA(bh, al, a);
        a = MFMA(bl, ah, a);
        acc3[j] = a;
      }
    }
    int n0 = nt*16 + 4*lg;
    float4 bv = *(const float4*)&b3[n0];
    float bvv[4] = {bv.x, bv.y, bv.z, bv.w};
    #pragma unroll
    for (int j=0;j<2;++j){
      int row = (rb+j)*16 + lr;
      float t4[4];
      unsigned short hb[4];
      #pragma unroll
      for (int i=0;i<4;++i){
        float v = acc3[j][i] + bvv[i];
        float e2 = __expf(2.f*v);
        float t  = 1.f - 2.f*__builtin_amdgcn_rcpf(e2 + 1.f);
        t4[i] = t;
        hb[i] = f2bf(t);               // RNE for final bf16 (feeds scores)
      }
      size_t gro = (rowbase + (size_t)row)*32 + n0;
      *(uint2*)&lifto[gro] = make_uint2((unsigned)hb[0] | ((unsigned)hb[1]<<16),
                                        (unsigned)hb[2] | ((unsigned)hb[3]<<16));
      if (net == 0)
        *(float4*)&kout[gro] = make_float4(t4[0], t4[1], t4[2], t4[3]);
    }
  }

  // ================= zero-fill tail: this block's upper-triangle tiles =========
  {
    int zs = (int)(((long long)bid    * 7680) >> 12);
    int ze = (int)(((long long)(bid+1)* 7680) >> 12);
    f32x4 z = {0.f,0.f,0.f,0.f};
    for (int zid = zs; zid < ze; ++zid){
      int zbh = zid / 120;
      int k   = zid % 120;               // k = tc*(tc-1)/2 + tr, tr < tc
      int ztc = (int)((1.0f + __builtin_sqrtf(1.0f + 8.0f*(float)k)) * 0.5f);
      while (ztc*(ztc-1)/2 > k) --ztc;
      while ((ztc+1)*ztc/2 <= k) ++ztc;
      int ztr = k - ztc*(ztc-1)/2;
      float* zb = oscores + (size_t)zbh*4194304 + (size_t)(ztr*128)*2048 + ztc*128;
      #pragma unroll
      for (int it=0; it<16; ++it){
        int idx = it*256 + tid;          // 0..4095
        int row = idx >> 5, c4 = idx & 31;
        *(f32x4*)&zb[(size_t)row*2048 + c4*4] = z;
      }
    }
  }
}

// ---------------- kernel 2 v5: LDS-transpose scores, lower+diag only, XCD swizzle ----
// Compute path byte-identical to R15. Upper tiles zeroed by lift's tail -> return.
__global__ __launch_bounds__(256) void scores_k(
    const unsigned short* __restrict__ qlift,
    const unsigned short* __restrict__ klift,
    float* __restrict__ out)
{
  int orig = blockIdx.x;
  int bid  = (orig & 7) * 2048 + (orig >> 3);   // bijective: 16384 % 8 == 0
  int tc = bid & 15, tr = (bid >> 4) & 15, bh = bid >> 8;
  if (tc > tr) return;   // zero-filled by lift tail
  size_t sbase = (size_t)bh * 2048 * 2048;
  int r0 = tr * 128, c0 = tc * 128;   // r0: t rows (Q), c0: s cols (K)
  int tid = threadIdx.x;

  __shared__ float sbuf[4][16][128];   // per-wave 8KB transpose buffer
  int w = tid >> 6, l = tid & 63;
  int lr = l & 15, lg = l >> 4;
  int acol0 = 8*lg;
  float* sw = &sbuf[w][0][0];

  // B operand: Q fragments for t-tiles {w*32, w*32+16}
  const unsigned short* qb = qlift + ((size_t)bh*2048 + r0 + w*32)*32;
  bf16x8 q0 = *(const bf16x8*)(qb + (size_t)lr*32 + acol0);
  bf16x8 q1 = *(const bf16x8*)(qb + (size_t)(16+lr)*32 + acol0);
  bool diag = (tc == tr);

  // A operand: K fragments for the 8 s-tiles (prefetch all, reused both passes)
  const unsigned short* kb = klift + ((size_t)bh*2048 + c0)*32;
  bf16x8 kf[8];
  #pragma unroll
  for (int st8=0; st8<8; ++st8)
    kf[st8] = *(const bf16x8*)(kb + (size_t)(st8*16+lr)*32 + acol0);

  #pragma unroll
  for (int pass=0; pass<2; ++pass){
    bf16x8 qf = pass ? q1 : q0;
    int tbase = r0 + w*32 + pass*16;   // global t of LDS row 0
    int t = tbase + lr;                // this lane's t (for diag predication)

    #pragma unroll
    for (int st8=0; st8<8; ++st8){
      f32x4 z4 = {0.f,0.f,0.f,0.f};
      f32x4 d = MFMA(kf[st8], qf, z4);   // D[row]=s (4lg+i), D[col]=t (lr)
      int scol = c0 + st8*16 + 4*lg;
      f32x4 p;
      #pragma unroll
      for (int i=0;i<4;++i){
        float pv = __builtin_amdgcn_rcpf(1.f + __expf(-d[i]));
        if (diag && (scol + i > t)) pv = 0.f;
        p[i] = pv;
      }
      int fi = (lr*128 + st8*16 + lg*4) ^ ((lr&7)<<2);   // XOR-swizzled float idx
      *(f32x4*)&sw[fi] = p;
    }
    // readback: 8 instructions, each stores TWO 512B contiguous row-bursts
    #pragma unroll
    for (int it=0; it<8; ++it){
      int r  = it*2 + (l>>5);            // LDS row 0..15
      int fi = (r*128 + (l&31)*4) ^ ((r&7)<<2);
      f32x4 v = *(const f32x4*)&sw[fi];
      *(f32x4*)&out[sbase + (size_t)(tbase + r)*2048 + c0 + (l&31)*4] = v;
    }
  }
}

extern "C" void kernel_launch(void* const* d_in, const int* in_sizes, int n_in,
                              void* d_out, int out_size, void* d_ws, size_t ws_size,
                              hipStream_t stream) {
  const float* K   = (const float*)d_in[0];
  const float* Q   = (const float*)d_in[1];
  const float* wk1 = (const float*)d_in[2];  const float* bk1 = (const float*)d_in[3];
  const float* wk2 = (const float*)d_in[4];  const float* bk2 = (const float*)d_in[5];
  const float* wk3 = (const float*)d_in[6];  const float* bk3 = (const float*)d_in[7];
  const float* wq1 = (const float*)d_in[8];  const float* bq1 = (const float*)d_in[9];
  const float* wq2 = (const float*)d_in[10]; const float* bq2 = (const float*)d_in[11];
  const float* wq3 = (const float*)d_in[12]; const float* bq3 = (const float*)d_in[13];
  float* out = (float*)d_out;

  unsigned short* ws    = (unsigned short*)d_ws;
  unsigned short* qlift = ws;                 // 4,194,304 ushorts
  unsigned short* klift = ws + 4194304;       // 4,194,304 ushorts
  unsigned short* wbase = ws + 8388608;       // 2 nets * 2,359,296 ushorts

  hipLaunchKernelGGL(wswz, dim3(256,6), dim3(256), 0, stream,
                     wk1, wk2, wk3, wq1, wq2, wq3, wbase);
  hipLaunchKernelGGL(lift, dim3(4096), dim3(256), 0, stream,
                     K, Q, bk1, bk2, bk3, bq1, bq2, bq3,
                     wbase, qlift, klift, out + 268435456ull, out);
  hipLaunchKernelGGL(scores_k, dim3(16384), dim3(256), 0, stream,
                     qlift, klift, out);
}

// Round 17
// 286.726 us; speedup vs baseline: 1.0480x; 1.0480x over previous
//
#include <hip/hip_runtime.h>

typedef __attribute__((ext_vector_type(8))) short bf16x8;
typedef __attribute__((ext_vector_type(4))) float f32x4;

#define MFMA(a,b,c) __builtin_amdgcn_mfma_f32_16x16x32_bf16(a,b,c,0,0,0)

static __device__ __forceinline__ unsigned short f2bf(float f){
  unsigned u = __float_as_uint(f);
  u += 0x7FFF + ((u>>16)&1);
  return (unsigned short)(u>>16);
}
static __device__ __forceinline__ float bf2f(unsigned short b){
  return __uint_as_float(((unsigned)b)<<16);
}

// ---------------- kernel 0: weight swizzle into MFMA fragment order, bf16 hi/lo ----
__global__ __launch_bounds__(256) void wswz(
    const float* __restrict__ wk1, const float* __restrict__ wk2, const float* __restrict__ wk3,
    const float* __restrict__ wq1, const float* __restrict__ wq2, const float* __restrict__ wq3,
    unsigned short* __restrict__ wb)
{
  int y = blockIdx.y;            // net*3 + layer
  int net = y / 3, layer = y % 3;
  const float* src = net ? (layer==0?wq1: layer==1?wq2:wq3)
                         : (layer==0?wk1: layer==1?wk2:wk3);
  int N  = (layer==2) ? 32 : 128;
  int NT = N / 16;
  int total = 32 * NT * 4 * 64;
  int e = blockIdx.x * 256 + threadIdx.x;
  if (e >= total) return;
  int lane = e & 63;
  int ks   = (e >> 6) & 3;
  int nt   = (e >> 8) % NT;
  int h    = (e >> 8) / NT;
  int k0 = ks*32 + 8*(lane>>4);
  int n0 = nt*16 + (lane&15);
  const float* s = src + (size_t)h*128*N + (size_t)k0*N + n0;
  unsigned short hi[8], lo[8];
  #pragma unroll
  for (int j=0;j<8;++j){
    float v = s[(size_t)j*N];
    unsigned short hh = f2bf(v);
    hi[j] = hh;
    lo[j] = f2bf(v - bf2f(hh));
  }
  size_t nb   = (size_t)net * 2359296;
  size_t loff = (layer==0) ? 0 : (layer==1) ? 1048576 : 2097152;
  size_t losz = (layer==2) ? 131072 : 524288;
  size_t eidx = ((((size_t)h*NT + nt)*4 + ks)*64 + lane)*8;
  unsigned short* dH = wb + nb + loff + eidx;
  unsigned short* dL = dH + losz;
  *(bf16x8*)dH = *(const bf16x8*)hi;
  *(bf16x8*)dL = *(const bf16x8*)lo;
}

// ---------------- kernel 1 (R10/R15 EXACT, no tail): per-head 3-layer MLP ----------
__global__ __launch_bounds__(256,3) void lift(
    const float* __restrict__ Kin, const float* __restrict__ Qin,
    const float* __restrict__ bk1, const float* __restrict__ bk2, const float* __restrict__ bk3,
    const float* __restrict__ bq1, const float* __restrict__ bq2, const float* __restrict__ bq3,
    const unsigned short* __restrict__ wb,
    unsigned short* __restrict__ qlift, unsigned short* __restrict__ klift,
    float* __restrict__ kout)
{
  __shared__ unsigned short XH[64][136];
  __shared__ unsigned short XL[64][136];
  int bid = blockIdx.x;
  int h   = (bid & 7)*4 + ((bid>>3)&3);   // XCD-packed head index
  int st  = (bid>>5) & 31;
  int bb  = (bid>>10) & 1;
  int net = bid>>11;
  size_t rowbase = (size_t)(bb*32 + h)*2048 + (size_t)st*64;
  const float* X = (net ? Qin : Kin) + rowbase*128;
  const unsigned short* wn = wb + (size_t)net*2359296;
  const float* b1 = (net ? bq1 : bk1) + h*128;
  const float* b2 = (net ? bq2 : bk2) + h*128;
  const float* b3 = (net ? bq3 : bk3) + h*32;
  unsigned short* lifto = net ? qlift : klift;

  int tid = threadIdx.x, w = tid >> 6, l = tid & 63;
  int lr = l & 15, lg = l >> 4;
  int acol0 = 8*lg;

  // stage 64 rows x 128 cols as trunc-split hi/lo into LDS (block-wide)
  #pragma unroll
  for (int i=0;i<8;++i){
    int row = i*8 + (tid>>5);
    int col = (tid&31)*4;
    float4 v = *(const float4*)&X[(size_t)row*128 + col];
    unsigned u0=__float_as_uint(v.x), u1=__float_as_uint(v.y),
             u2=__float_as_uint(v.z), u3=__float_as_uint(v.w);
    float l0 = v.x - __uint_as_float(u0 & 0xFFFF0000u);
    float l1 = v.y - __uint_as_float(u1 & 0xFFFF0000u);
    float l2 = v.z - __uint_as_float(u2 & 0xFFFF0000u);
    float l3 = v.w - __uint_as_float(u3 & 0xFFFF0000u);
    *(uint2*)&XH[row][col] = make_uint2((u0>>16) | (u1 & 0xFFFF0000u),
                                        (u2>>16) | (u3 & 0xFFFF0000u));
    *(uint2*)&XL[row][col] = make_uint2((__float_as_uint(l0)>>16) | (__float_as_uint(l1) & 0xFFFF0000u),
                                        (__float_as_uint(l2)>>16) | (__float_as_uint(l3) & 0xFFFF0000u));
  }
  __syncthreads();

  // ================= layers 1 & 2 (K=128 -> N=128, silu) =================
  for (int L=0; L<2; ++L){
    const unsigned short* wH = wn + (size_t)L*1048576;
    const unsigned short* wL = wH + 524288;
    const float* bias = L ? b2 : b1;
    f32x4 acc[2][4];
    #pragma unroll
    for (int ntl=0;ntl<2;++ntl)
      #pragma unroll
      for (int rt=0;rt<4;++rt)
        acc[ntl][rt] = (f32x4){0.f,0.f,0.f,0.f};

    #pragma unroll
    for (int ks=0;ks<4;++ks){
      bf16x8 bh[2], bl[2];
      #pragma unroll
      for (int ntl=0;ntl<2;++ntl){
        size_t eidx = ((((size_t)h*8 + (w*2+ntl))*4 + ks)*64 + l)*8;
        bh[ntl] = *(const bf16x8*)(wH + eidx);
        bl[ntl] = *(const bf16x8*)(wL + eidx);
      }
      #pragma unroll
      for (int rt=0;rt<4;++rt){
        bf16x8 ah = *(const bf16x8*)&XH[rt*16+lr][ks*32 + acol0];
        bf16x8 al = *(const bf16x8*)&XL[rt*16+lr][ks*32 + acol0];
        #pragma unroll
        for (int ntl=0;ntl<2;++ntl){
          f32x4 a = acc[ntl][rt];
          a = MFMA(bh[ntl], ah, a);   // Wh * Xh
          a = MFMA(bh[ntl], al, a);   // Wh * Xl
          a = MFMA(bl[ntl], ah, a);   // Wl * Xh
          acc[ntl][rt] = a;
        }
      }
    }
    __syncthreads();   // all reads of previous acts complete before overwrite
    #pragma unroll
    for (int ntl=0;ntl<2;++ntl){
      int n0 = (w*2+ntl)*16 + 4*lg;   // 4 consecutive output features
      float4 bv = *(const float4*)&bias[n0];
      float bvv[4] = {bv.x, bv.y, bv.z, bv.w};
      #pragma unroll
      for (int rt=0;rt<4;++rt){
        int row = rt*16 + lr;          // act row owned by this lane
        unsigned hh[4], ll[4];
        #pragma unroll
        for (int i=0;i<4;++i){
          float v = acc[ntl][rt][i] + bvv[i];
          float sg = v * __builtin_amdgcn_rcpf(1.f + __expf(-v));
          unsigned u = __float_as_uint(sg);
          hh[i] = u >> 16;
          float lo = sg - __uint_as_float(u & 0xFFFF0000u);
          ll[i] = __float_as_uint(lo) >> 16;
        }
        *(uint2*)&XH[row][n0] = make_uint2(hh[0] | (hh[1]<<16), hh[2] | (hh[3]<<16));
        *(uint2*)&XL[row][n0] = make_uint2(ll[0] | (ll[1]<<16), ll[2] | (ll[3]<<16));
      }
    }
    __syncthreads();
  }

  // ================= layer 3 (K=128 -> N=32, tanh) + packed stores =================
  {
    const unsigned short* wH = wn + 2097152;
    const unsigned short* wL = wH + 131072;
    int nt = w >> 1;
    int rb = (w & 1) * 2;
    f32x4 acc3[2];
    acc3[0] = (f32x4){0.f,0.f,0.f,0.f};
    acc3[1] = (f32x4){0.f,0.f,0.f,0.f};
    #pragma unroll
    for (int ks=0;ks<4;++ks){
      size_t eidx = ((((size_t)h*2 + nt)*4 + ks)*64 + l)*8;
      bf16x8 bh = *(const bf16x8*)(wH + eidx);
      bf16x8 bl = *(const bf16x8*)(wL + eidx);
      #pragma unroll
      for (int j=0;j<2;++j){
        bf16x8 ah = *(const bf16x8*)&XH[(rb+j)*16+lr][ks*32 + acol0];
        bf16x8 al = *(const bf16x8*)&XL[(rb+j)*16+lr][ks*32 + acol0];
        f32x4 a = acc3[j];
        a = MFMA(bh, ah, a);
        a = MFMA(bh, al, a);
        a = MFMA(bl, ah, a);
        acc3[j] = a;
      }
    }
    int n0 = nt*16 + 4*lg;
    float4 bv = *(const float4*)&b3[n0];
    float bvv[4] = {bv.x, bv.y, bv.z, bv.w};
    #pragma unroll
    for (int j=0;j<2;++j){
      int row = (rb+j)*16 + lr;
      float t4[4];
      unsigned short hb[4];
      #pragma unroll
      for (int i=0;i<4;++i){
        float v = acc3[j][i] + bvv[i];
        float e2 = __expf(2.f*v);
        float t  = 1.f - 2.f*__builtin_amdgcn_rcpf(e2 + 1.f);
        t4[i] = t;
        hb[i] = f2bf(t);               // RNE for final bf16 (feeds scores)
      }
      size_t gro = (rowbase + (size_t)row)*32 + n0;
      *(uint2*)&lifto[gro] = make_uint2((unsigned)hb[0] | ((unsigned)hb[1]<<16),
                                        (unsigned)hb[2] | ((unsigned)hb[3]<<16));
      if (net == 0)
        *(float4*)&kout[gro] = make_float4(t4[0], t4[1], t4[2], t4[3]);
    }
  }
}

// ---------------- kernel 2 v6: ROW-SLAB scores, contiguous 128KB block footprint ----
// R17 change (isolated vs R15): block = 16 consecutive t-rows x FULL 2048 s of one
// bh -> all block writes land in ONE contiguous 128KB region (R15: 64KB scattered
// 512B-bursts over a 1MB span, new DRAM page per burst). Rows are written start-
// to-end: compute windows below the diagonal via the R14 LDS-transpose (wave-
// private, no barriers), zero windows past it as direct streaming stores — no
// separate zero pass anywhere. R6's row-slab failure modes both fixed: stores are
// 512B bursts (not scattered 64B), and the XCD-chunk swizzle keeps each bh's
// 128KB klift L2-resident (R6 re-read ~1GB from HBM).
__global__ __launch_bounds__(256) void scores_k(
    const unsigned short* __restrict__ qlift,
    const unsigned short* __restrict__ klift,
    float* __restrict__ out)
{
  int orig = blockIdx.x;
  int bid  = (orig & 7) * 1024 + (orig >> 3);   // bijective: 8192 % 8 == 0
  int sl = bid & 127;            // 16-row slab within bh
  int bh = bid >> 7;
  int T0 = sl * 16;
  int diagW = sl >> 3;           // 128-col window containing the diagonal
  int tid = threadIdx.x, w = tid >> 6, l = tid & 63;
  int lr = l & 15, lg = l >> 4;
  int acol0 = 8*lg;

  __shared__ float sbuf[4][16][128];   // per-wave 8KB transpose buffer
  float* sw = &sbuf[w][0][0];

  const unsigned short* qb = qlift + ((size_t)bh*2048 + T0)*32;
  bf16x8 qf = *(const bf16x8*)(qb + (size_t)lr*32 + acol0);
  const unsigned short* kbh = klift + (size_t)bh*2048*32;
  size_t obase = (size_t)bh*4194304 + (size_t)T0*2048;
  f32x4 z4 = {0.f,0.f,0.f,0.f};
  int t = T0 + lr;               // this lane's t row (for diag predication)

  for (int W = w; W < 16; W += 4){
    int c0 = W*128;
    if (W <= diagW){
      const unsigned short* kb = kbh + (size_t)c0*32;
      bool dg = (W == diagW);
      #pragma unroll
      for (int st8=0; st8<8; ++st8){
        bf16x8 kf = *(const bf16x8*)(kb + (size_t)(st8*16+lr)*32 + acol0);
        f32x4 d = MFMA(kf, qf, z4);      // D[row]=s (4lg+i), D[col]=t (lr)
        int scol = c0 + st8*16 + 4*lg;
        f32x4 p;
        #pragma unroll
        for (int i=0;i<4;++i){
          float pv = __builtin_amdgcn_rcpf(1.f + __expf(-d[i]));
          if (dg && (scol + i > t)) pv = 0.f;
          p[i] = pv;
        }
        int fi = (lr*128 + st8*16 + lg*4) ^ ((lr&7)<<2);   // XOR-swizzled float idx
        *(f32x4*)&sw[fi] = p;
      }
      #pragma unroll
      for (int it=0; it<8; ++it){
        int r  = it*2 + (l>>5);          // slab row 0..15
        int fi = (r*128 + (l&31)*4) ^ ((r&7)<<2);
        f32x4 v = *(const f32x4*)&sw[fi];
        *(f32x4*)&out[obase + (size_t)r*2048 + c0 + (l&31)*4] = v;
      }
    } else {
      #pragma unroll
      for (int it=0; it<8; ++it){
        int r = it*2 + (l>>5);
        *(f32x4*)&out[obase + (size_t)r*2048 + c0 + (l&31)*4] = z4;
      }
    }
  }
}

extern "C" void kernel_launch(void* const* d_in, const int* in_sizes, int n_in,
                              void* d_out, int out_size, void* d_ws, size_t ws_size,
                              hipStream_t stream) {
  const float* K   = (const float*)d_in[0];
  const float* Q   = (const float*)d_in[1];
  const float* wk1 = (const float*)d_in[2];  const float* bk1 = (const float*)d_in[3];
  const float* wk2 = (const float*)d_in[4];  const float* bk2 = (const float*)d_in[5];
  const float* wk3 = (const float*)d_in[6];  const float* bk3 = (const float*)d_in[7];
  const float* wq1 = (const float*)d_in[8];  const float* bq1 = (const float*)d_in[9];
  const float* wq2 = (const float*)d_in[10]; const float* bq2 = (const float*)d_in[11];
  const float* wq3 = (const float*)d_in[12]; const float* bq3 = (const float*)d_in[13];
  float* out = (float*)d_out;

  unsigned short* ws    = (unsigned short*)d_ws;
  unsigned short* qlift = ws;                 // 4,194,304 ushorts
  unsigned short* klift = ws + 4194304;       // 4,194,304 ushorts
  unsigned short* wbase = ws + 8388608;       // 2 nets * 2,359,296 ushorts

  hipLaunchKernelGGL(wswz, dim3(256,6), dim3(256), 0, stream,
                     wk1, wk2, wk3, wq1, wq2, wq3, wbase);
  hipLaunchKernelGGL(lift, dim3(4096), dim3(256), 0, stream,
                     K, Q, bk1, bk2, bk3, bq1, bq2, bq3,
                     wbase, qlift, klift, out + 268435456ull);
  hipLaunchKernelGGL(scores_k, dim3(8192), dim3(256), 0, stream,
                     qlift, klift, out);
}

// Round 18
// 279.235 us; speedup vs baseline: 1.0761x; 1.0268x over previous
//
#include <hip/hip_runtime.h>

typedef __attribute__((ext_vector_type(8))) short bf16x8;
typedef __attribute__((ext_vector_type(4))) float f32x4;

#define MFMA(a,b,c) __builtin_amdgcn_mfma_f32_16x16x32_bf16(a,b,c,0,0,0)

static __device__ __forceinline__ unsigned short f2bf(float f){
  unsigned u = __float_as_uint(f);
  u += 0x7FFF + ((u>>16)&1);
  return (unsigned short)(u>>16);
}
static __device__ __forceinline__ float bf2f(unsigned short b){
  return __uint_as_float(((unsigned)b)<<16);
}

// ---------------- kernel 0: weight swizzle into MFMA fragment order, bf16 hi/lo ----
__global__ __launch_bounds__(256) void wswz(
    const float* __restrict__ wk1, const float* __restrict__ wk2, const float* __restrict__ wk3,
    const float* __restrict__ wq1, const float* __restrict__ wq2, const float* __restrict__ wq3,
    unsigned short* __restrict__ wb)
{
  int y = blockIdx.y;            // net*3 + layer
  int net = y / 3, layer = y % 3;
  const float* src = net ? (layer==0?wq1: layer==1?wq2:wq3)
                         : (layer==0?wk1: layer==1?wk2:wk3);
  int N  = (layer==2) ? 32 : 128;
  int NT = N / 16;
  int total = 32 * NT * 4 * 64;
  int e = blockIdx.x * 256 + threadIdx.x;
  if (e >= total) return;
  int lane = e & 63;
  int ks   = (e >> 6) & 3;
  int nt   = (e >> 8) % NT;
  int h    = (e >> 8) / NT;
  int k0 = ks*32 + 8*(lane>>4);
  int n0 = nt*16 + (lane&15);
  const float* s = src + (size_t)h*128*N + (size_t)k0*N + n0;
  unsigned short hi[8], lo[8];
  #pragma unroll
  for (int j=0;j<8;++j){
    float v = s[(size_t)j*N];
    unsigned short hh = f2bf(v);
    hi[j] = hh;
    lo[j] = f2bf(v - bf2f(hh));
  }
  size_t nb   = (size_t)net * 2359296;
  size_t loff = (layer==0) ? 0 : (layer==1) ? 1048576 : 2097152;
  size_t losz = (layer==2) ? 131072 : 524288;
  size_t eidx = ((((size_t)h*NT + nt)*4 + ks)*64 + lane)*8;
  unsigned short* dH = wb + nb + loff + eidx;
  unsigned short* dL = dH + losz;
  *(bf16x8*)dH = *(const bf16x8*)hi;
  *(bf16x8*)dL = *(const bf16x8*)lo;
}

// ---------------- kernel 1 (R10 EXACT): per-head 3-layer MLP, swapped-operand MFMA ----
__global__ __launch_bounds__(256,3) void lift(
    const float* __restrict__ Kin, const float* __restrict__ Qin,
    const float* __restrict__ bk1, const float* __restrict__ bk2, const float* __restrict__ bk3,
    const float* __restrict__ bq1, const float* __restrict__ bq2, const float* __restrict__ bq3,
    const unsigned short* __restrict__ wb,
    unsigned short* __restrict__ qlift, unsigned short* __restrict__ klift,
    float* __restrict__ kout)
{
  __shared__ unsigned short XH[64][136];
  __shared__ unsigned short XL[64][136];
  int bid = blockIdx.x;
  int h   = (bid & 7)*4 + ((bid>>3)&3);   // XCD-packed head index
  int st  = (bid>>5) & 31;
  int bb  = (bid>>10) & 1;
  int net = bid>>11;
  size_t rowbase = (size_t)(bb*32 + h)*2048 + (size_t)st*64;
  const float* X = (net ? Qin : Kin) + rowbase*128;
  const unsigned short* wn = wb + (size_t)net*2359296;
  const float* b1 = (net ? bq1 : bk1) + h*128;
  const float* b2 = (net ? bq2 : bk2) + h*128;
  const float* b3 = (net ? bq3 : bk3) + h*32;
  unsigned short* lifto = net ? qlift : klift;

  int tid = threadIdx.x, w = tid >> 6, l = tid & 63;
  int lr = l & 15, lg = l >> 4;
  int acol0 = 8*lg;

  // stage 64 rows x 128 cols as trunc-split hi/lo into LDS (block-wide)
  #pragma unroll
  for (int i=0;i<8;++i){
    int row = i*8 + (tid>>5);
    int col = (tid&31)*4;
    float4 v = *(const float4*)&X[(size_t)row*128 + col];
    unsigned u0=__float_as_uint(v.x), u1=__float_as_uint(v.y),
             u2=__float_as_uint(v.z), u3=__float_as_uint(v.w);
    float l0 = v.x - __uint_as_float(u0 & 0xFFFF0000u);
    float l1 = v.y - __uint_as_float(u1 & 0xFFFF0000u);
    float l2 = v.z - __uint_as_float(u2 & 0xFFFF0000u);
    float l3 = v.w - __uint_as_float(u3 & 0xFFFF0000u);
    *(uint2*)&XH[row][col] = make_uint2((u0>>16) | (u1 & 0xFFFF0000u),
                                        (u2>>16) | (u3 & 0xFFFF0000u));
    *(uint2*)&XL[row][col] = make_uint2((__float_as_uint(l0)>>16) | (__float_as_uint(l1) & 0xFFFF0000u),
                                        (__float_as_uint(l2)>>16) | (__float_as_uint(l3) & 0xFFFF0000u));
  }
  __syncthreads();

  // ================= layers 1 & 2 (K=128 -> N=128, silu) =================
  for (int L=0; L<2; ++L){
    const unsigned short* wH = wn + (size_t)L*1048576;
    const unsigned short* wL = wH + 524288;
    const float* bias = L ? b2 : b1;
    f32x4 acc[2][4];
    #pragma unroll
    for (int ntl=0;ntl<2;++ntl)
      #pragma unroll
      for (int rt=0;rt<4;++rt)
        acc[ntl][rt] = (f32x4){0.f,0.f,0.f,0.f};

    #pragma unroll
    for (int ks=0;ks<4;++ks){
      bf16x8 bh[2], bl[2];
      #pragma unroll
      for (int ntl=0;ntl<2;++ntl){
        size_t eidx = ((((size_t)h*8 + (w*2+ntl))*4 + ks)*64 + l)*8;
        bh[ntl] = *(const bf16x8*)(wH + eidx);
        bl[ntl] = *(const bf16x8*)(wL + eidx);
      }
      #pragma unroll
      for (int rt=0;rt<4;++rt){
        bf16x8 ah = *(const bf16x8*)&XH[rt*16+lr][ks*32 + acol0];
        bf16x8 al = *(const bf16x8*)&XL[rt*16+lr][ks*32 + acol0];
        #pragma unroll
        for (int ntl=0;ntl<2;++ntl){
          f32x4 a = acc[ntl][rt];
          a = MFMA(bh[ntl], ah, a);   // Wh * Xh
          a = MFMA(bh[ntl], al, a);   // Wh * Xl
          a = MFMA(bl[ntl], ah, a);   // Wl * Xh
          acc[ntl][rt] = a;
        }
      }
    }
    __syncthreads();   // all reads of previous acts complete before overwrite
    #pragma unroll
    for (int ntl=0;ntl<2;++ntl){
      int n0 = (w*2+ntl)*16 + 4*lg;   // 4 consecutive output features
      float4 bv = *(const float4*)&bias[n0];
      float bvv[4] = {bv.x, bv.y, bv.z, bv.w};
      #pragma unroll
      for (int rt=0;rt<4;++rt){
        int row = rt*16 + lr;          // act row owned by this lane
        unsigned hh[4], ll[4];
        #pragma unroll
        for (int i=0;i<4;++i){
          float v = acc[ntl][rt][i] + bvv[i];
          float sg = v * __builtin_amdgcn_rcpf(1.f + __expf(-v));
          unsigned u = __float_as_uint(sg);
          hh[i] = u >> 16;
          float lo = sg - __uint_as_float(u & 0xFFFF0000u);
          ll[i] = __float_as_uint(lo) >> 16;
        }
        *(uint2*)&XH[row][n0] = make_uint2(hh[0] | (hh[1]<<16), hh[2] | (hh[3]<<16));
        *(uint2*)&XL[row][n0] = make_uint2(ll[0] | (ll[1]<<16), ll[2] | (ll[3]<<16));
      }
    }
    __syncthreads();
  }

  // ================= layer 3 (K=128 -> N=32, tanh) + packed stores =================
  {
    const unsigned short* wH = wn + 2097152;
    const unsigned short* wL = wH + 131072;
    int nt = w >> 1;
    int rb = (w & 1) * 2;
    f32x4 acc3[2];
    acc3[0] = (f32x4){0.f,0.f,0.f,0.f};
    acc3[1] = (f32x4){0.f,0.f,0.f,0.f};
    #pragma unroll
    for (int ks=0;ks<4;++ks){
      size_t eidx = ((((size_t)h*2 + nt)*4 + ks)*64 + l)*8;
      bf16x8 bh = *(const bf16x8*)(wH + eidx);
      bf16x8 bl = *(const bf16x8*)(wL + eidx);
      #pragma unroll
      for (int j=0;j<2;++j){
        bf16x8 ah = *(const bf16x8*)&XH[(rb+j)*16+lr][ks*32 + acol0];
        bf16x8 al = *(const bf16x8*)&XL[(rb+j)*16+lr][ks*32 + acol0];
        f32x4 a = acc3[j];
        a = MFMA(bh, ah, a);
        a = MFMA(bh, al, a);
        a = MFMA(bl, ah, a);
        acc3[j] = a;
      }
    }
    int n0 = nt*16 + 4*lg;
    float4 bv = *(const float4*)&b3[n0];
    float bvv[4] = {bv.x, bv.y, bv.z, bv.w};
    #pragma unroll
    for (int j=0;j<2;++j){
      int row = (rb+j)*16 + lr;
      float t4[4];
      unsigned short hb[4];
      #pragma unroll
      for (int i=0;i<4;++i){
        float v = acc3[j][i] + bvv[i];
        float e2 = __expf(2.f*v);
        float t  = 1.f - 2.f*__builtin_amdgcn_rcpf(e2 + 1.f);
        t4[i] = t;
        hb[i] = f2bf(t);               // RNE for final bf16 (feeds scores)
      }
      size_t gro = (rowbase + (size_t)row)*32 + n0;
      *(uint2*)&lifto[gro] = make_uint2((unsigned)hb[0] | ((unsigned)hb[1]<<16),
                                        (unsigned)hb[2] | ((unsigned)hb[3]<<16));
      if (net == 0)
        *(float4*)&kout[gro] = make_float4(t4[0], t4[1], t4[2], t4[3]);
    }
  }
}

// ---------------- kernel 2 (R15 EXACT, best 279.9us): LDS-transpose + XCD swizzle ----
__global__ __launch_bounds__(256) void scores_k(
    const unsigned short* __restrict__ qlift,
    const unsigned short* __restrict__ klift,
    float* __restrict__ out)
{
  int orig = blockIdx.x;
  int bid  = (orig & 7) * 2048 + (orig >> 3);   // bijective: 16384 % 8 == 0
  int tc = bid & 15, tr = (bid >> 4) & 15, bh = bid >> 8;
  size_t sbase = (size_t)bh * 2048 * 2048;
  int r0 = tr * 128, c0 = tc * 128;   // r0: t rows (Q), c0: s cols (K)
  int tid = threadIdx.x;

  if (tc > tr){ // fully masked tile: sigmoid(f32_min) == 0
    float4 z = {0.f,0.f,0.f,0.f};
    #pragma unroll
    for (int it=0; it<16; ++it){
      int idx = it*256 + tid;     // 0..4095
      int row = idx >> 5, c4 = idx & 31;
      *(float4*)&out[sbase + (size_t)(r0+row)*2048 + c0 + c4*4] = z;
    }
    return;
  }

  __shared__ float sbuf[4][16][128];   // per-wave 8KB transpose buffer
  int w = tid >> 6, l = tid & 63;
  int lr = l & 15, lg = l >> 4;
  int acol0 = 8*lg;
  float* sw = &sbuf[w][0][0];

  // B operand: Q fragments for t-tiles {w*32, w*32+16}
  const unsigned short* qb = qlift + ((size_t)bh*2048 + r0 + w*32)*32;
  bf16x8 q0 = *(const bf16x8*)(qb + (size_t)lr*32 + acol0);
  bf16x8 q1 = *(const bf16x8*)(qb + (size_t)(16+lr)*32 + acol0);
  bool diag = (tc == tr);

  // A operand: K fragments for the 8 s-tiles (prefetch all, reused both passes)
  const unsigned short* kb = klift + ((size_t)bh*2048 + c0)*32;
  bf16x8 kf[8];
  #pragma unroll
  for (int st8=0; st8<8; ++st8)
    kf[st8] = *(const bf16x8*)(kb + (size_t)(st8*16+lr)*32 + acol0);

  #pragma unroll
  for (int pass=0; pass<2; ++pass){
    bf16x8 qf = pass ? q1 : q0;
    int tbase = r0 + w*32 + pass*16;   // global t of LDS row 0
    int t = tbase + lr;                // this lane's t (for diag predication)

    #pragma unroll
    for (int st8=0; st8<8; ++st8){
      f32x4 z4 = {0.f,0.f,0.f,0.f};
      f32x4 d = MFMA(kf[st8], qf, z4);   // D[row]=s (4lg+i), D[col]=t (lr)
      int scol = c0 + st8*16 + 4*lg;
      f32x4 p;
      #pragma unroll
      for (int i=0;i<4;++i){
        float pv = __builtin_amdgcn_rcpf(1.f + __expf(-d[i]));
        if (diag && (scol + i > t)) pv = 0.f;
        p[i] = pv;
      }
      int fi = (lr*128 + st8*16 + lg*4) ^ ((lr&7)<<2);   // XOR-swizzled float idx
      *(f32x4*)&sw[fi] = p;
    }
    // readback: 8 instructions, each stores TWO 512B contiguous row-bursts
    #pragma unroll
    for (int it=0; it<8; ++it){
      int r  = it*2 + (l>>5);            // LDS row 0..15
      int fi = (r*128 + (l&31)*4) ^ ((r&7)<<2);
      f32x4 v = *(const f32x4*)&sw[fi];
      *(f32x4*)&out[sbase + (size_t)(tbase + r)*2048 + c0 + (l&31)*4] = v;
    }
  }
}

extern "C" void kernel_launch(void* const* d_in, const int* in_sizes, int n_in,
                              void* d_out, int out_size, void* d_ws, size_t ws_size,
                              hipStream_t stream) {
  const float* K   = (const float*)d_in[0];
  const float* Q   = (const float*)d_in[1];
  const float* wk1 = (const float*)d_in[2];  const float* bk1 = (const float*)d_in[3];
  const float* wk2 = (const float*)d_in[4];  const float* bk2 = (const float*)d_in[5];
  const float* wk3 = (const float*)d_in[6];  const float* bk3 = (const float*)d_in[7];
  const float* wq1 = (const float*)d_in[8];  const float* bq1 = (const float*)d_in[9];
  const float* wq2 = (const float*)d_in[10]; const float* bq2 = (const float*)d_in[11];
  const float* wq3 = (const float*)d_in[12]; const float* bq3 = (const float*)d_in[13];
  float* out = (float*)d_out;

  unsigned short* ws    = (unsigned short*)d_ws;
  unsigned short* qlift = ws;                 // 4,194,304 ushorts
  unsigned short* klift = ws + 4194304;       // 4,194,304 ushorts
  unsigned short* wbase = ws + 8388608;       // 2 nets * 2,359,296 ushorts

  hipLaunchKernelGGL(wswz, dim3(256,6), dim3(256), 0, stream,
                     wk1, wk2, wk3, wq1, wq2, wq3, wbase);
  hipLaunchKernelGGL(lift, dim3(4096), dim3(256), 0, stream,
                     K, Q, bk1, bk2, bk3, bq1, bq2, bq3,
                     wbase, qlift, klift, out + 268435456ull);
  hipLaunchKernelGGL(scores_k, dim3(16384), dim3(256), 0, stream,
                     qlift, klift, out);
}